// Round 4
// baseline (14581.291 us; speedup 1.0000x reference)
//
#include <hip/hip_runtime.h>
#include <math.h>

#define N_   4096
#define E_   128
#define H_   256
#define G4_  1024
#define SCALE_T 2.8853900817779268f   // 2*log2(e): exp2(S*x) = e^(2x)
#define L2E_    1.4426950408889634f   // log2(e)
#define NEG_BIG -1.0e30f              // finite stand-in for -inf
#define SENT_U  0x7FC00001u           // qNaN sentinel: h is always finite
#define NBLK_   64                    // launched blocks for the scan
#define TEAM_   8                     // worker blocks (one XCD)

__device__ __forceinline__ float sigm_fast(float x) {
    return __builtin_amdgcn_rcpf(1.f + __builtin_amdgcn_exp2f(-L2E_ * x));
}
__device__ __forceinline__ float tanh_fast(float x) {
    return 1.f - 2.f * __builtin_amdgcn_rcpf(1.f + __builtin_amdgcn_exp2f(SCALE_T * x));
}

// comm ops: LOCAL=1 -> sc0 (L1-bypass, XCD-L2 coherent); LOCAL=0 -> agent scope (LLC)
template<int LOCAL>
__device__ __forceinline__ unsigned comm_ld(const unsigned* __restrict__ p) {
    unsigned u;
    if constexpr (LOCAL) {
        asm volatile("global_load_dword %0, %1, off sc0\n\ts_waitcnt vmcnt(0)"
                     : "=v"(u) : "v"(p) : "memory");
    } else {
        u = __hip_atomic_load(p, __ATOMIC_RELAXED, __HIP_MEMORY_SCOPE_AGENT);
    }
    return u;
}
template<int LOCAL>
__device__ __forceinline__ void comm_st(unsigned* __restrict__ p, unsigned v) {
    if constexpr (LOCAL) {
        asm volatile("global_store_dword %0, %1, off sc0" :: "v"(p), "v"(v) : "memory");
    } else {
        __hip_atomic_store(p, v, __ATOMIC_RELAXED, __HIP_MEMORY_SCOPE_AGENT);
    }
}

// ---------------------------------------------------------------------------
// init: pos[i]=INF, tour tail of d_out, zero256, negv2, sumv, regs zeroing
// ---------------------------------------------------------------------------
__global__ __launch_bounds__(256) void init_misc(
    const int* __restrict__ tour, const float* __restrict__ v,
    float* __restrict__ out_tail, int* __restrict__ pos,
    float* __restrict__ zero256, float* __restrict__ negv2, float* __restrict__ sumv,
    int* __restrict__ regs)
{
    const int i = blockIdx.x * 256 + threadIdx.x;
    if (i < N_) {
        pos[i] = 0x7FFFFFFF;
        out_tail[i] = (float)tour[i];
    }
    if (blockIdx.x == 0) {
        __shared__ float red[256];
        const float vv = v[threadIdx.x];
        negv2[threadIdx.x] = -2.f * vv;
        zero256[threadIdx.x] = 0.f;
        if (threadIdx.x < 64) regs[threadIdx.x] = 0;
        red[threadIdx.x] = vv;
        __syncthreads();
        for (int s = 128; s > 0; s >>= 1) {
            if (threadIdx.x < s) red[threadIdx.x] += red[threadIdx.x + s];
            __syncthreads();
        }
        if (threadIdx.x == 0) sumv[0] = red[0];
    }
}

// sentinel-fill encout & hx (each N_*H_ floats)
__global__ __launch_bounds__(256) void fill_sent(uint4* __restrict__ a, uint4* __restrict__ b)
{
    const int i = blockIdx.x * 256 + threadIdx.x;   // 1024*256 = N_*H_/4
    const uint4 s = make_uint4(SENT_U, SENT_U, SENT_U, SENT_U);
    a[i] = s;
    b[i] = s;
}

__global__ __launch_bounds__(256) void pos_scatter(
    const int* __restrict__ tour, int* __restrict__ pos)
{
    const int i = blockIdx.x * 256 + threadIdx.x;
    if (i < N_) atomicMin(&pos[tour[i]], i);
}

// ---------------------------------------------------------------------------
// embeddings
// ---------------------------------------------------------------------------
__global__ __launch_bounds__(256) void embed2(
    const float* __restrict__ x,
    const float* __restrict__ eW, const float* __restrict__ eb,
    const float* __restrict__ cW, const float* __restrict__ cb,
    float* __restrict__ emb, float* __restrict__ city)
{
    const int m = blockIdx.x, tid = threadIdx.x;
    const float x0 = x[2*m], x1 = x[2*m+1];
    if (tid < E_) {
        emb[(size_t)m*E_ + tid] = x0*eW[2*tid] + x1*eW[2*tid+1] + eb[tid];
    } else {
        const int e = tid - E_;
        city[(size_t)m*E_ + e] = x0*cW[2*e] + x1*cW[2*e+1] + cb[e];
    }
}

__global__ __launch_bounds__(128) void gather_dec(
    const float* __restrict__ city, const float* __restrict__ st,
    const int* __restrict__ tour, float* __restrict__ dseq)
{
    const int t = blockIdx.x, e = threadIdx.x;
    dseq[(size_t)t*E_ + e] = (t == 0) ? st[e] : city[(size_t)tour[t-1]*E_ + e];
}

// ---------------------------------------------------------------------------
// generic fp32 GEMM: C[M,N] = scale*(A[M,K] @ B[N,K]^T) (+b0) (+b1); storeT opt
// ---------------------------------------------------------------------------
__global__ __launch_bounds__(256) void gemm64(
    const float* __restrict__ A, const float* __restrict__ B, float* __restrict__ C,
    int M, int N, int K, const float* __restrict__ b0, const float* __restrict__ b1,
    float scale, int storeT)
{
    __shared__ float As[16][68];
    __shared__ float Bs[16][68];
    const int tid = threadIdx.x;
    const int m0 = blockIdx.y * 64, n0 = blockIdx.x * 64;
    const int tx = tid & 15, ty = tid >> 4;
    const int lr = tid >> 2, lk = (tid & 3) * 4;
    float acc[4][4] = {};
    for (int kb = 0; kb < K; kb += 16) {
        const float4 a4 = *(const float4*)&A[(size_t)(m0+lr)*K + kb + lk];
        const float4 b4 = *(const float4*)&B[(size_t)(n0+lr)*K + kb + lk];
        __syncthreads();
        As[lk][lr]=a4.x; As[lk+1][lr]=a4.y; As[lk+2][lr]=a4.z; As[lk+3][lr]=a4.w;
        Bs[lk][lr]=b4.x; Bs[lk+1][lr]=b4.y; Bs[lk+2][lr]=b4.z; Bs[lk+3][lr]=b4.w;
        __syncthreads();
        #pragma unroll
        for (int k = 0; k < 16; ++k) {
            const float4 av4 = *(const float4*)&As[k][ty*4];
            const float4 bv4 = *(const float4*)&Bs[k][tx*4];
            const float avv[4] = {av4.x, av4.y, av4.z, av4.w};
            const float bvv[4] = {bv4.x, bv4.y, bv4.z, bv4.w};
            #pragma unroll
            for (int i = 0; i < 4; ++i)
                #pragma unroll
                for (int j = 0; j < 4; ++j)
                    acc[i][j] += avv[i] * bvv[j];
        }
    }
    #pragma unroll
    for (int i = 0; i < 4; ++i) {
        const int m = m0 + ty*4 + i;
        #pragma unroll
        for (int j = 0; j < 4; ++j) {
            const int n = n0 + tx*4 + j;
            float val = scale * acc[i][j];
            if (b0) val += b0[n];
            if (b1) val += b1[n];
            if (storeT) C[(size_t)n*M + m] = val;
            else        C[(size_t)m*N + n] = val;
        }
    }
}

// ---------------------------------------------------------------------------
// LSTM scan v3: TEAM_=8 blocks x 256 thr on ONE XCD (verified via handshake).
// Block g owns l-slice [g*32,(g+1)*32) of h => 128 gate rows. Wave w owns
// k-slice [64w,64w+64): its sentinel-poll lands h[64w+j] in lane j; the
// 128x64 matvec runs as 64x {readlane broadcast + 2 fmac} — no LDS stream.
// 2 barriers/step. Weights (128 fp32/thread) register-resident.
// ---------------------------------------------------------------------------
template<int LOCAL>
__device__ void scan_phase3(const float* __restrict__ xih, float* __restrict__ outbuf,
                            const float* __restrict__ prev,
                            const float (&w0)[64], const float (&w1)[64],
                            float& c_loc, float (*psum)[128], float* actb,
                            int g, int t)
{
    const int wv = t >> 6, j = t & 63;
    const int grow = ((t & 127) >> 5)*256 + g*32 + (t & 31);   // for t<128 (xv/act)
    for (int s = 0; s < N_; ++s) {
        float xv = 0.f;
        if (t < 128) xv = xih[(size_t)s*G4_ + grow];           // hides under the poll
        const float* hsrc = s ? (outbuf + (size_t)(s-1)*H_) : prev;
        const unsigned* hp = (const unsigned*)hsrc + t;
        unsigned u = comm_ld<LOCAL>(hp);
        while (u == SENT_U) u = comm_ld<LOCAL>(hp);
        const float hval = __uint_as_float(u);                 // h[wv*64 + j]
        float a0 = 0.f, a1 = 0.f;
        #pragma unroll
        for (int jj = 0; jj < 64; ++jj) {
            const float sv = __uint_as_float(
                __builtin_amdgcn_readlane(__float_as_uint(hval), jj));
            a0 = fmaf(w0[jj], sv, a0);                         // local row j
            a1 = fmaf(w1[jj], sv, a1);                         // local row 64+j
        }
        psum[wv][j] = a0;
        psum[wv][64 + j] = a1;
        __syncthreads();   // psum(s) complete. next psum write is after bar2(s).
        if (t < 128) {
            const float gate = xv + ((psum[0][t] + psum[1][t]) + (psum[2][t] + psum[3][t]));
            actb[t] = ((t >> 5) == 2) ? tanh_fast(gate) : sigm_fast(gate);
        }
        __syncthreads();   // actb(s) complete. next actb write is after bar1(s+1),
                           // which waits for the update thread's reads below.
        if (t < 32) {
            const float iv = actb[t], fv = actb[32+t], gv = actb[64+t], ov = actb[96+t];
            c_loc = fv * c_loc + iv * gv;
            const float hn = ov * tanh_fast(c_loc);
            comm_st<LOCAL>((unsigned*)&outbuf[(size_t)s*H_ + g*32 + t], __float_as_uint(hn));
        }
    }
}

template<int LOCAL>
__device__ void run_scan(const float* __restrict__ exih, const float* __restrict__ ewhh,
                         const float* __restrict__ dxih, const float* __restrict__ dwhh,
                         const float* __restrict__ zero256,
                         float* __restrict__ encout, float* __restrict__ hx,
                         float (*psum)[128], float* actb, int g, int t)
{
    const int wv = t >> 6, j = t & 63;
    const int grow0 = (j >> 5)*256 + g*32 + (j & 31);   // local row j   (gates i/f)
    const int grow1 = grow0 + 512;                      // local row 64+j (gates g/o)
    float w0[64], w1[64];
    #pragma unroll
    for (int k = 0; k < 64; k += 4) {
        *(float4*)&w0[k] = *(const float4*)&ewhh[(size_t)grow0*256 + wv*64 + k];
        *(float4*)&w1[k] = *(const float4*)&ewhh[(size_t)grow1*256 + wv*64 + k];
    }
    float c_loc = 0.f;
    scan_phase3<LOCAL>(exih, encout, zero256, w0, w1, c_loc, psum, actb, g, t);
    #pragma unroll
    for (int k = 0; k < 64; k += 4) {
        *(float4*)&w0[k] = *(const float4*)&dwhh[(size_t)grow0*256 + wv*64 + k];
        *(float4*)&w1[k] = *(const float4*)&dwhh[(size_t)grow1*256 + wv*64 + k];
    }
    scan_phase3<LOCAL>(dxih, hx, encout + (size_t)(N_-1)*H_, w0, w1, c_loc, psum, actb, g, t);
}

// regs layout: [0]=tot, [1..8]=per-XCD cnt, [16..23]=token1, [24..31]=verdict,
//              [32..39]=token2
__global__ __launch_bounds__(256, 1) void lstm_scan3(
    const float* __restrict__ exih, const float* __restrict__ ewhh,
    const float* __restrict__ dxih, const float* __restrict__ dwhh,
    const float* __restrict__ zero256, float* __restrict__ encout,
    float* __restrict__ hx, int* __restrict__ regs)
{
    __shared__ float psum[4][128];
    __shared__ float actb[128];
    __shared__ int sh_g, sh_ok;
    const int t = threadIdx.x;

    // ---- registration: group blocks by physical XCD ----
    if (t == 0) {
        unsigned xcd;
        asm volatile("s_getreg_b32 %0, hwreg(HW_REG_XCC_ID, 0, 32)" : "=s"(xcd));
        xcd &= 7u;
        const int slot = __hip_atomic_fetch_add(&regs[1 + xcd], 1, __ATOMIC_RELAXED,
                                                __HIP_MEMORY_SCOPE_AGENT);
        __hip_atomic_fetch_add(&regs[0], 1, __ATOMIC_RELEASE, __HIP_MEMORY_SCOPE_AGENT);
        while (__hip_atomic_load(&regs[0], __ATOMIC_ACQUIRE, __HIP_MEMORY_SCOPE_AGENT) < NBLK_)
            __builtin_amdgcn_s_sleep(2);
        int tx = 0;
        for (int xx = 7; xx >= 0; --xx)
            if (__hip_atomic_load(&regs[1 + xx], __ATOMIC_RELAXED,
                                  __HIP_MEMORY_SCOPE_AGENT) >= TEAM_) tx = xx;
        sh_g = ((int)xcd == tx && slot < TEAM_) ? slot : -1;
    }
    __syncthreads();
    const int g = sh_g;
    if (g < 0) return;

    // ---- sc0 handshake: verify L2-local visibility, else fall back ----
    if (t == 0) {
        // round 1: presence via sc0
        comm_st<1>((unsigned*)&regs[16 + g], 0x00A10000u + (unsigned)g);
        int ok1 = 0;
        for (int it = 0; it < 1500 && !ok1; ++it) {
            ok1 = 1;
            for (int o = 0; o < TEAM_; ++o)
                ok1 &= (comm_ld<1>((const unsigned*)&regs[16 + o]) == 0x00A10000u + (unsigned)o);
        }
        // round 2: stale-retention probe — prime reader caches BEFORE stores land
        for (int o = 0; o < TEAM_; ++o) (void)comm_ld<1>((const unsigned*)&regs[32 + o]);
        comm_st<1>((unsigned*)&regs[32 + g], 0x00B20000u + (unsigned)g);
        int ok2 = 0;
        for (int it = 0; it < 1500 && !ok2; ++it) {
            ok2 = 1;
            for (int o = 0; o < TEAM_; ++o)
                ok2 &= (comm_ld<1>((const unsigned*)&regs[32 + o]) == 0x00B20000u + (unsigned)o);
        }
        __hip_atomic_store(&regs[24 + g], (ok1 && ok2) ? 2 : 1, __ATOMIC_RELEASE,
                           __HIP_MEMORY_SCOPE_AGENT);
        int allok = 1;
        for (int o = 0; o < TEAM_; ++o) {
            int vo;
            do { vo = __hip_atomic_load(&regs[24 + o], __ATOMIC_ACQUIRE,
                                        __HIP_MEMORY_SCOPE_AGENT); } while (vo == 0);
            allok &= (vo == 2);
        }
        sh_ok = allok;
    }
    __syncthreads();

    if (sh_ok) run_scan<1>(exih, ewhh, dxih, dwhh, zero256, encout, hx, psum, actb, g, t);
    else       run_scan<0>(exih, ewhh, dxih, dwhh, zero256, encout, hx, psum, actb, g, t);
}

// ---------------------------------------------------------------------------
// attention scores
// ---------------------------------------------------------------------------
#define TI_ 32
#define TT_ 16

__global__ __launch_bounds__(256) void attn_scores(
    const float* __restrict__ projT, const float* __restrict__ Umat,
    const float* __restrict__ negv2, const float* __restrict__ sumvp,
    const int* __restrict__ pos, float* __restrict__ out)
{
    const int i0 = blockIdx.x * TI_, t0 = blockIdx.y * TT_;
    const int tid = threadIdx.x;
    const int lane = tid & 63, wv = tid >> 6;
    const int il = lane & 31, th = lane >> 5;
    const int pi = pos[i0 + il];
    if (__all(pi < t0)) {
        for (int idx = tid; idx < TT_*TI_; idx += 256) {
            const int r = idx >> 5, c = idx & 31;
            out[(size_t)(t0 + r)*N_ + i0 + c] = NEG_BIG;
        }
        return;
    }
    __shared__ float pTs[256][33];
    __shared__ float Us[TT_][256];
    __shared__ float vsh[256];
    vsh[tid] = negv2[tid];
    #pragma unroll
    for (int dd = 0; dd < 8; ++dd) {
        const int d = (tid >> 3) + dd*32;
        const float4 p4 = *(const float4*)&projT[(size_t)d*N_ + i0 + (tid & 7)*4];
        const int c = (tid & 7)*4;
        pTs[d][c] = p4.x; pTs[d][c+1] = p4.y; pTs[d][c+2] = p4.z; pTs[d][c+3] = p4.w;
    }
    for (int idx = tid; idx < TT_*256; idx += 256) {
        const int r = idx >> 8, c = idx & 255;
        Us[r][c] = Umat[(size_t)(t0 + r)*H_ + c];
    }
    __syncthreads();
    const float sumv = sumvp[0];
    #pragma unroll
    for (int pass = 0; pass < 2; ++pass) {
        const int tl = pass*8 + wv*2 + th;
        const int t = t0 + tl;
        float a0 = 0.f, a1 = 0.f, a2 = 0.f, a3 = 0.f;
        #pragma unroll 8
        for (int d = 0; d < 256; d += 4) {
            const float x0 = pTs[d  ][il] + Us[tl][d  ];
            const float x1 = pTs[d+1][il] + Us[tl][d+1];
            const float x2 = pTs[d+2][il] + Us[tl][d+2];
            const float x3 = pTs[d+3][il] + Us[tl][d+3];
            a0 += vsh[d  ] * __builtin_amdgcn_rcpf(1.f + exp2f(x0));
            a1 += vsh[d+1] * __builtin_amdgcn_rcpf(1.f + exp2f(x1));
            a2 += vsh[d+2] * __builtin_amdgcn_rcpf(1.f + exp2f(x2));
            a3 += vsh[d+3] * __builtin_amdgcn_rcpf(1.f + exp2f(x3));
        }
        float val = sumv + ((a0 + a1) + (a2 + a3));
        if (pi < t) val = NEG_BIG;
        out[(size_t)t*N_ + i0 + il] = val;
    }
}

// in-place row log_softmax
__global__ __launch_bounds__(256) void logsm(float* __restrict__ out)
{
    const int t = blockIdx.x, tid = threadIdx.x;
    float* row = out + (size_t)t*N_;
    float v[16];
    float lmax = NEG_BIG;
    #pragma unroll
    for (int j = 0; j < 16; ++j) { v[j] = row[tid + j*256]; lmax = fmaxf(lmax, v[j]); }
    __shared__ float red[256];
    red[tid] = lmax; __syncthreads();
    for (int s = 128; s > 0; s >>= 1) {
        if (tid < s) red[tid] = fmaxf(red[tid], red[tid + s]);
        __syncthreads();
    }
    const float m = red[0];
    __syncthreads();
    float lsum = 0.f;
    #pragma unroll
    for (int j = 0; j < 16; ++j) lsum += __expf(v[j] - m);
    red[tid] = lsum; __syncthreads();
    for (int s = 128; s > 0; s >>= 1) {
        if (tid < s) red[tid] += red[tid + s];
        __syncthreads();
    }
    const float lse = m + logf(red[0]);
    #pragma unroll
    for (int j = 0; j < 16; ++j) row[tid + j*256] = v[j] - lse;
}

// ---------------------------------------------------------------------------
extern "C" void kernel_launch(void* const* d_in, const int* in_sizes, int n_in,
                              void* d_out, int out_size, void* d_ws, size_t ws_size,
                              hipStream_t stream)
{
    const float* x        = (const float*)d_in[0];
    const int*   tour     = (const int*)  d_in[1];
    const float* eW       = (const float*)d_in[2];
    const float* eb       = (const float*)d_in[3];
    const float* enc_Wih  = (const float*)d_in[4];
    const float* enc_Whh  = (const float*)d_in[5];
    const float* enc_bih  = (const float*)d_in[6];
    const float* enc_bhh  = (const float*)d_in[7];
    const float* dec_Wih  = (const float*)d_in[8];
    const float* dec_Whh  = (const float*)d_in[9];
    const float* dec_bih  = (const float*)d_in[10];
    const float* dec_bhh  = (const float*)d_in[11];
    const float* W1       = (const float*)d_in[12];
    const float* W2       = (const float*)d_in[13];
    const float* attv     = (const float*)d_in[14];
    const float* cW       = (const float*)d_in[15];
    const float* cb       = (const float*)d_in[16];
    const float* st       = (const float*)d_in[17];
    float* out = (float*)d_out;

    float* ws = (float*)d_ws;
    size_t o = 0;
    float* emb    = ws + o; o += (size_t)N_*E_;
    float* city   = ws + o; o += (size_t)N_*E_;
    float* dseq   = ws + o; o += (size_t)N_*E_;
    float* exih   = ws + o; o += (size_t)N_*G4_;
    float* dxih   = ws + o; o += (size_t)N_*G4_;
    float* encout = ws + o; o += (size_t)N_*H_;
    float* hx     = ws + o; o += (size_t)N_*H_;
    float* projT  = ws + o; o += (size_t)N_*H_;   // [H_][N_] transposed (pre-scaled)
    float* Umat   = ws + o; o += (size_t)N_*H_;   // [N_][H_]  (pre-scaled)
    float* negv2  = ws + o; o += 256;
    float* sumv   = ws + o; o += 64;
    float* zero256= ws + o; o += 256;
    int* regs     = (int*)(ws + o); o += 64;
    int* pos      = (int*)(ws + o); o += N_;

    init_misc  <<<16, 256, 0, stream>>>(tour, attv, out + (size_t)N_*N_, pos, zero256, negv2, sumv, regs);
    fill_sent  <<<1024, 256, 0, stream>>>((uint4*)encout, (uint4*)hx);
    pos_scatter<<<16, 256, 0, stream>>>(tour, pos);
    embed2     <<<N_, 256, 0, stream>>>(x, eW, eb, cW, cb, emb, city);
    gather_dec <<<N_, 128, 0, stream>>>(city, st, tour, dseq);
    gemm64<<<dim3(G4_/64, N_/64), 256, 0, stream>>>(emb,  enc_Wih, exih, N_, G4_, E_, enc_bih, enc_bhh, 1.f, 0);
    gemm64<<<dim3(G4_/64, N_/64), 256, 0, stream>>>(dseq, dec_Wih, dxih, N_, G4_, E_, dec_bih, dec_bhh, 1.f, 0);
    lstm_scan3<<<NBLK_, 256, 0, stream>>>(exih, enc_Whh, dxih, dec_Whh, zero256, encout, hx, regs);
    gemm64<<<dim3(H_/64, N_/64), 256, 0, stream>>>(encout, W1, projT, N_, H_, H_, nullptr, nullptr, SCALE_T, 1);
    gemm64<<<dim3(H_/64, N_/64), 256, 0, stream>>>(hx,     W2, Umat,  N_, H_, H_, nullptr, nullptr, SCALE_T, 0);
    attn_scores<<<dim3(N_/TI_, N_/TT_), 256, 0, stream>>>(projT, Umat, negv2, sumv, pos, out);
    logsm<<<N_, 256, 0, stream>>>(out);
}

// Round 5
// 12993.782 us; speedup vs baseline: 1.1222x; 1.1222x over previous
//
#include <hip/hip_runtime.h>
#include <math.h>

#define N_   4096
#define E_   128
#define H_   256
#define G4_  1024
#define SCALE_T 2.8853900817779268f   // 2*log2(e): exp2(S*x) = e^(2x)
#define L2E_    1.4426950408889634f   // log2(e)
#define NEG_BIG -1.0e30f              // finite stand-in for -inf
#define SENT_U  0x7FC00001u           // qNaN sentinel: h is always finite
#define NBLK_   64                    // launched blocks for the scan
#define TEAM_   8                     // worker blocks (one XCD)

__device__ __forceinline__ float sigm_fast(float x) {
    return __builtin_amdgcn_rcpf(1.f + __builtin_amdgcn_exp2f(-L2E_ * x));
}
__device__ __forceinline__ float tanh_fast(float x) {
    return 1.f - 2.f * __builtin_amdgcn_rcpf(1.f + __builtin_amdgcn_exp2f(SCALE_T * x));
}

// comm ops: LOCAL=1 -> sc0 (L1-bypass, XCD-L2 coherent); LOCAL=0 -> agent scope (LLC)
template<int LOCAL>
__device__ __forceinline__ unsigned comm_ld(const unsigned* __restrict__ p) {
    unsigned u;
    if constexpr (LOCAL) {
        asm volatile("global_load_dword %0, %1, off sc0\n\ts_waitcnt vmcnt(0)"
                     : "=v"(u) : "v"(p) : "memory");
    } else {
        u = __hip_atomic_load(p, __ATOMIC_RELAXED, __HIP_MEMORY_SCOPE_AGENT);
    }
    return u;
}
template<int LOCAL>
__device__ __forceinline__ void comm_st(unsigned* __restrict__ p, unsigned v) {
    if constexpr (LOCAL) {
        asm volatile("global_store_dword %0, %1, off sc0" :: "v"(p), "v"(v) : "memory");
    } else {
        __hip_atomic_store(p, v, __ATOMIC_RELAXED, __HIP_MEMORY_SCOPE_AGENT);
    }
}

// ---------------------------------------------------------------------------
// init: pos[i]=INF, tour tail of d_out, zero256, negv2, sumv, regs zeroing
// ---------------------------------------------------------------------------
__global__ __launch_bounds__(256) void init_misc(
    const int* __restrict__ tour, const float* __restrict__ v,
    float* __restrict__ out_tail, int* __restrict__ pos,
    float* __restrict__ zero256, float* __restrict__ negv2, float* __restrict__ sumv,
    int* __restrict__ regs)
{
    const int i = blockIdx.x * 256 + threadIdx.x;
    if (i < N_) {
        pos[i] = 0x7FFFFFFF;
        out_tail[i] = (float)tour[i];
    }
    if (blockIdx.x == 0) {
        __shared__ float red[256];
        const float vv = v[threadIdx.x];
        negv2[threadIdx.x] = -2.f * vv;
        zero256[threadIdx.x] = 0.f;
        if (threadIdx.x < 64) regs[threadIdx.x] = 0;
        red[threadIdx.x] = vv;
        __syncthreads();
        for (int s = 128; s > 0; s >>= 1) {
            if (threadIdx.x < s) red[threadIdx.x] += red[threadIdx.x + s];
            __syncthreads();
        }
        if (threadIdx.x == 0) sumv[0] = red[0];
    }
}

// sentinel-fill encout & hx (each N_*H_ floats)
__global__ __launch_bounds__(256) void fill_sent(uint4* __restrict__ a, uint4* __restrict__ b)
{
    const int i = blockIdx.x * 256 + threadIdx.x;   // 1024*256 = N_*H_/4
    const uint4 s = make_uint4(SENT_U, SENT_U, SENT_U, SENT_U);
    a[i] = s;
    b[i] = s;
}

__global__ __launch_bounds__(256) void pos_scatter(
    const int* __restrict__ tour, int* __restrict__ pos)
{
    const int i = blockIdx.x * 256 + threadIdx.x;
    if (i < N_) atomicMin(&pos[tour[i]], i);
}

// ---------------------------------------------------------------------------
// embeddings
// ---------------------------------------------------------------------------
__global__ __launch_bounds__(256) void embed2(
    const float* __restrict__ x,
    const float* __restrict__ eW, const float* __restrict__ eb,
    const float* __restrict__ cW, const float* __restrict__ cb,
    float* __restrict__ emb, float* __restrict__ city)
{
    const int m = blockIdx.x, tid = threadIdx.x;
    const float x0 = x[2*m], x1 = x[2*m+1];
    if (tid < E_) {
        emb[(size_t)m*E_ + tid] = x0*eW[2*tid] + x1*eW[2*tid+1] + eb[tid];
    } else {
        const int e = tid - E_;
        city[(size_t)m*E_ + e] = x0*cW[2*e] + x1*cW[2*e+1] + cb[e];
    }
}

__global__ __launch_bounds__(128) void gather_dec(
    const float* __restrict__ city, const float* __restrict__ st,
    const int* __restrict__ tour, float* __restrict__ dseq)
{
    const int t = blockIdx.x, e = threadIdx.x;
    dseq[(size_t)t*E_ + e] = (t == 0) ? st[e] : city[(size_t)tour[t-1]*E_ + e];
}

// ---------------------------------------------------------------------------
// generic fp32 GEMM: C[M,N] = scale*(A[M,K] @ B[N,K]^T) (+b0) (+b1); storeT opt
// ---------------------------------------------------------------------------
__global__ __launch_bounds__(256) void gemm64(
    const float* __restrict__ A, const float* __restrict__ B, float* __restrict__ C,
    int M, int N, int K, const float* __restrict__ b0, const float* __restrict__ b1,
    float scale, int storeT)
{
    __shared__ float As[16][68];
    __shared__ float Bs[16][68];
    const int tid = threadIdx.x;
    const int m0 = blockIdx.y * 64, n0 = blockIdx.x * 64;
    const int tx = tid & 15, ty = tid >> 4;
    const int lr = tid >> 2, lk = (tid & 3) * 4;
    float acc[4][4] = {};
    for (int kb = 0; kb < K; kb += 16) {
        const float4 a4 = *(const float4*)&A[(size_t)(m0+lr)*K + kb + lk];
        const float4 b4 = *(const float4*)&B[(size_t)(n0+lr)*K + kb + lk];
        __syncthreads();
        As[lk][lr]=a4.x; As[lk+1][lr]=a4.y; As[lk+2][lr]=a4.z; As[lk+3][lr]=a4.w;
        Bs[lk][lr]=b4.x; Bs[lk+1][lr]=b4.y; Bs[lk+2][lr]=b4.z; Bs[lk+3][lr]=b4.w;
        __syncthreads();
        #pragma unroll
        for (int k = 0; k < 16; ++k) {
            const float4 av4 = *(const float4*)&As[k][ty*4];
            const float4 bv4 = *(const float4*)&Bs[k][tx*4];
            const float avv[4] = {av4.x, av4.y, av4.z, av4.w};
            const float bvv[4] = {bv4.x, bv4.y, bv4.z, bv4.w};
            #pragma unroll
            for (int i = 0; i < 4; ++i)
                #pragma unroll
                for (int j = 0; j < 4; ++j)
                    acc[i][j] += avv[i] * bvv[j];
        }
    }
    #pragma unroll
    for (int i = 0; i < 4; ++i) {
        const int m = m0 + ty*4 + i;
        #pragma unroll
        for (int j = 0; j < 4; ++j) {
            const int n = n0 + tx*4 + j;
            float val = scale * acc[i][j];
            if (b0) val += b0[n];
            if (b1) val += b1[n];
            if (storeT) C[(size_t)n*M + m] = val;
            else        C[(size_t)m*N + n] = val;
        }
    }
}

// ---------------------------------------------------------------------------
// LSTM scan v4: TEAM_=8 blocks x 256 thr on one XCD (handshake-verified sc0,
// agent-scope fallback). Block g owns h slice [g*32,(g+1)*32) => 128 gate
// rows. Wave w polls k-slice h[64w..64w+64) (lane j holds h[64w+j]); matvec
// = 64x {readlane + 2 fmac} with weights in TRUE registers (float4 arrays,
// static indices only -- no address-taken casts, the R2-R4 scratch bug).
// ONE barrier/step: parity-double-buffered psum; wave0 alone does gates +
// c/h update + sc0 store while waves 1-3 run ahead to the next poll.
// ---------------------------------------------------------------------------
__device__ __forceinline__ void load_wregs(const float* __restrict__ whh,
                                           int grow0, int grow1, int wv,
                                           float4 (&w0)[16], float4 (&w1)[16])
{
    const float4* p0 = (const float4*)(whh + (size_t)grow0*256 + wv*64);
    const float4* p1 = (const float4*)(whh + (size_t)grow1*256 + wv*64);
    #pragma unroll
    for (int i = 0; i < 16; ++i) { w0[i] = p0[i]; w1[i] = p1[i]; }
}

template<int LOCAL>
__device__ __forceinline__ void scan_phase4(
    const float* __restrict__ xih, float* __restrict__ outbuf,
    const float* __restrict__ prev, const float4 (&w0)[16], const float4 (&w1)[16],
    float& c_loc, float (*psum)[4][128], int g, int t)
{
    const int wv = t >> 6, j = t & 63;
    const int up = (t < 32);
    float xv0=0.f, xv1=0.f, xv2=0.f, xv3=0.f, xn0=0.f, xn1=0.f, xn2=0.f, xn3=0.f;
    if (up) {
        const float* xb = xih + g*32 + t;
        xv0 = xb[0]; xv1 = xb[256]; xv2 = xb[512]; xv3 = xb[768];
    }
    for (int s = 0; s < N_; ++s) {
        const int p = s & 1;
        const float* hsrc = s ? (outbuf + (size_t)(s-1)*H_) : prev;
        const unsigned* hp = (const unsigned*)hsrc + t;
        unsigned u = comm_ld<LOCAL>(hp);
        while (u == SENT_U) u = comm_ld<LOCAL>(hp);
        const float hval = __uint_as_float(u);
        if (up) {   // prefetch next step's x_ih; consumed after the update
            const float* xb = xih + (size_t)(s+1)*G4_ + g*32 + t;
            xn0 = xb[0]; xn1 = xb[256]; xn2 = xb[512]; xn3 = xb[768];
        }
        float a0 = 0.f, a1 = 0.f;
        #pragma unroll
        for (int i4 = 0; i4 < 16; ++i4) {
            const float4 wa = w0[i4], wb = w1[i4];
            float sv;
            sv = __uint_as_float(__builtin_amdgcn_readlane(__float_as_uint(hval), 4*i4+0));
            a0 = fmaf(wa.x, sv, a0); a1 = fmaf(wb.x, sv, a1);
            sv = __uint_as_float(__builtin_amdgcn_readlane(__float_as_uint(hval), 4*i4+1));
            a0 = fmaf(wa.y, sv, a0); a1 = fmaf(wb.y, sv, a1);
            sv = __uint_as_float(__builtin_amdgcn_readlane(__float_as_uint(hval), 4*i4+2));
            a0 = fmaf(wa.z, sv, a0); a1 = fmaf(wb.z, sv, a1);
            sv = __uint_as_float(__builtin_amdgcn_readlane(__float_as_uint(hval), 4*i4+3));
            a0 = fmaf(wa.w, sv, a0); a1 = fmaf(wb.w, sv, a1);
        }
        psum[p][wv][j]      = a0;   // local gate-row j      (q = j>>5 : i/f)
        psum[p][wv][64 + j] = a1;   // local gate-row 64+j   (q = 2+(j>>5) : g/o)
        __syncthreads();
        // RAW: barrier orders all psum[p] writes before wave0's reads.
        // WAR: psum[p] is rewritten at s+2, which is transitively ordered after
        // these reads via h(s+1)'s data dependency (see analysis).
        if (up) {
            float pre0 = xv0, pre1 = xv1, pre2 = xv2, pre3 = xv3;
            #pragma unroll
            for (int w2 = 0; w2 < 4; ++w2) {
                pre0 += psum[p][w2][t];
                pre1 += psum[p][w2][32 + t];
                pre2 += psum[p][w2][64 + t];
                pre3 += psum[p][w2][96 + t];
            }
            const float iv = sigm_fast(pre0);
            const float fv = sigm_fast(pre1);
            const float gv = tanh_fast(pre2);
            const float ov = sigm_fast(pre3);
            c_loc = fv * c_loc + iv * gv;
            const float hn = ov * tanh_fast(c_loc);
            comm_st<LOCAL>((unsigned*)&outbuf[(size_t)s*H_ + g*32 + t], __float_as_uint(hn));
            xv0 = xn0; xv1 = xn1; xv2 = xn2; xv3 = xn3;
        }
    }
}

template<int LOCAL>
__device__ void run_scan(const float* __restrict__ exih, const float* __restrict__ ewhh,
                         const float* __restrict__ dxih, const float* __restrict__ dwhh,
                         const float* __restrict__ zero256,
                         float* __restrict__ encout, float* __restrict__ hx,
                         float (*psum)[4][128], int g, int t)
{
    const int wv = t >> 6, j = t & 63;
    const int grow0 = (j >> 5)*256 + g*32 + (j & 31);   // gate-rows j (i/f)
    const int grow1 = grow0 + 512;                      // gate-rows 64+j (g/o)
    float4 w0[16], w1[16];
    load_wregs(ewhh, grow0, grow1, wv, w0, w1);
    float c_loc = 0.f;
    scan_phase4<LOCAL>(exih, encout, zero256, w0, w1, c_loc, psum, g, t);
    load_wregs(dwhh, grow0, grow1, wv, w0, w1);
    scan_phase4<LOCAL>(dxih, hx, encout + (size_t)(N_-1)*H_, w0, w1, c_loc, psum, g, t);
}

// regs layout: [0]=tot, [1..8]=per-XCD cnt, [16..23]=token1, [24..31]=verdict,
//              [32..39]=token2
__global__ __launch_bounds__(256, 1) void lstm_scan4(
    const float* __restrict__ exih, const float* __restrict__ ewhh,
    const float* __restrict__ dxih, const float* __restrict__ dwhh,
    const float* __restrict__ zero256, float* __restrict__ encout,
    float* __restrict__ hx, int* __restrict__ regs)
{
    __shared__ float psum[2][4][128];
    __shared__ int sh_g, sh_ok;
    const int t = threadIdx.x;

    // ---- registration: group blocks by physical XCD ----
    if (t == 0) {
        unsigned xcd;
        asm volatile("s_getreg_b32 %0, hwreg(HW_REG_XCC_ID, 0, 32)" : "=s"(xcd));
        xcd &= 7u;
        const int slot = __hip_atomic_fetch_add(&regs[1 + xcd], 1, __ATOMIC_RELAXED,
                                                __HIP_MEMORY_SCOPE_AGENT);
        __hip_atomic_fetch_add(&regs[0], 1, __ATOMIC_RELEASE, __HIP_MEMORY_SCOPE_AGENT);
        while (__hip_atomic_load(&regs[0], __ATOMIC_ACQUIRE, __HIP_MEMORY_SCOPE_AGENT) < NBLK_)
            __builtin_amdgcn_s_sleep(2);
        int tx = 0;
        for (int xx = 7; xx >= 0; --xx)
            if (__hip_atomic_load(&regs[1 + xx], __ATOMIC_RELAXED,
                                  __HIP_MEMORY_SCOPE_AGENT) >= TEAM_) tx = xx;
        sh_g = ((int)xcd == tx && slot < TEAM_) ? slot : -1;
    }
    __syncthreads();
    const int g = sh_g;
    if (g < 0) return;

    // ---- sc0 handshake: verify L2-local visibility, else fall back ----
    if (t == 0) {
        comm_st<1>((unsigned*)&regs[16 + g], 0x00A10000u + (unsigned)g);
        int ok1 = 0;
        for (int it = 0; it < 1500 && !ok1; ++it) {
            ok1 = 1;
            for (int o = 0; o < TEAM_; ++o)
                ok1 &= (comm_ld<1>((const unsigned*)&regs[16 + o]) == 0x00A10000u + (unsigned)o);
        }
        for (int o = 0; o < TEAM_; ++o) (void)comm_ld<1>((const unsigned*)&regs[32 + o]);
        comm_st<1>((unsigned*)&regs[32 + g], 0x00B20000u + (unsigned)g);
        int ok2 = 0;
        for (int it = 0; it < 1500 && !ok2; ++it) {
            ok2 = 1;
            for (int o = 0; o < TEAM_; ++o)
                ok2 &= (comm_ld<1>((const unsigned*)&regs[32 + o]) == 0x00B20000u + (unsigned)o);
        }
        __hip_atomic_store(&regs[24 + g], (ok1 && ok2) ? 2 : 1, __ATOMIC_RELEASE,
                           __HIP_MEMORY_SCOPE_AGENT);
        int allok = 1;
        for (int o = 0; o < TEAM_; ++o) {
            int vo;
            do { vo = __hip_atomic_load(&regs[24 + o], __ATOMIC_ACQUIRE,
                                        __HIP_MEMORY_SCOPE_AGENT); } while (vo == 0);
            allok &= (vo == 2);
        }
        sh_ok = allok;
    }
    __syncthreads();

    if (sh_ok) run_scan<1>(exih, ewhh, dxih, dwhh, zero256, encout, hx, psum, g, t);
    else       run_scan<0>(exih, ewhh, dxih, dwhh, zero256, encout, hx, psum, g, t);
}

// ---------------------------------------------------------------------------
// attention scores
// ---------------------------------------------------------------------------
#define TI_ 32
#define TT_ 16

__global__ __launch_bounds__(256) void attn_scores(
    const float* __restrict__ projT, const float* __restrict__ Umat,
    const float* __restrict__ negv2, const float* __restrict__ sumvp,
    const int* __restrict__ pos, float* __restrict__ out)
{
    const int i0 = blockIdx.x * TI_, t0 = blockIdx.y * TT_;
    const int tid = threadIdx.x;
    const int lane = tid & 63, wv = tid >> 6;
    const int il = lane & 31, th = lane >> 5;
    const int pi = pos[i0 + il];
    if (__all(pi < t0)) {
        for (int idx = tid; idx < TT_*TI_; idx += 256) {
            const int r = idx >> 5, c = idx & 31;
            out[(size_t)(t0 + r)*N_ + i0 + c] = NEG_BIG;
        }
        return;
    }
    __shared__ float pTs[256][33];
    __shared__ float Us[TT_][256];
    __shared__ float vsh[256];
    vsh[tid] = negv2[tid];
    #pragma unroll
    for (int dd = 0; dd < 8; ++dd) {
        const int d = (tid >> 3) + dd*32;
        const float4 p4 = *(const float4*)&projT[(size_t)d*N_ + i0 + (tid & 7)*4];
        const int c = (tid & 7)*4;
        pTs[d][c] = p4.x; pTs[d][c+1] = p4.y; pTs[d][c+2] = p4.z; pTs[d][c+3] = p4.w;
    }
    for (int idx = tid; idx < TT_*256; idx += 256) {
        const int r = idx >> 8, c = idx & 255;
        Us[r][c] = Umat[(size_t)(t0 + r)*H_ + c];
    }
    __syncthreads();
    const float sumv = sumvp[0];
    #pragma unroll
    for (int pass = 0; pass < 2; ++pass) {
        const int tl = pass*8 + wv*2 + th;
        const int t = t0 + tl;
        float a0 = 0.f, a1 = 0.f, a2 = 0.f, a3 = 0.f;
        #pragma unroll 8
        for (int d = 0; d < 256; d += 4) {
            const float x0 = pTs[d  ][il] + Us[tl][d  ];
            const float x1 = pTs[d+1][il] + Us[tl][d+1];
            const float x2 = pTs[d+2][il] + Us[tl][d+2];
            const float x3 = pTs[d+3][il] + Us[tl][d+3];
            a0 += vsh[d  ] * __builtin_amdgcn_rcpf(1.f + exp2f(x0));
            a1 += vsh[d+1] * __builtin_amdgcn_rcpf(1.f + exp2f(x1));
            a2 += vsh[d+2] * __builtin_amdgcn_rcpf(1.f + exp2f(x2));
            a3 += vsh[d+3] * __builtin_amdgcn_rcpf(1.f + exp2f(x3));
        }
        float val = sumv + ((a0 + a1) + (a2 + a3));
        if (pi < t) val = NEG_BIG;
        out[(size_t)t*N_ + i0 + il] = val;
    }
}

// in-place row log_softmax
__global__ __launch_bounds__(256) void logsm(float* __restrict__ out)
{
    const int t = blockIdx.x, tid = threadIdx.x;
    float* row = out + (size_t)t*N_;
    float v[16];
    float lmax = NEG_BIG;
    #pragma unroll
    for (int j = 0; j < 16; ++j) { v[j] = row[tid + j*256]; lmax = fmaxf(lmax, v[j]); }
    __shared__ float red[256];
    red[tid] = lmax; __syncthreads();
    for (int s = 128; s > 0; s >>= 1) {
        if (tid < s) red[tid] = fmaxf(red[tid], red[tid + s]);
        __syncthreads();
    }
    const float m = red[0];
    __syncthreads();
    float lsum = 0.f;
    #pragma unroll
    for (int j = 0; j < 16; ++j) lsum += __expf(v[j] - m);
    red[tid] = lsum; __syncthreads();
    for (int s = 128; s > 0; s >>= 1) {
        if (tid < s) red[tid] += red[tid + s];
        __syncthreads();
    }
    const float lse = m + logf(red[0]);
    #pragma unroll
    for (int j = 0; j < 16; ++j) row[tid + j*256] = v[j] - lse;
}

// ---------------------------------------------------------------------------
extern "C" void kernel_launch(void* const* d_in, const int* in_sizes, int n_in,
                              void* d_out, int out_size, void* d_ws, size_t ws_size,
                              hipStream_t stream)
{
    const float* x        = (const float*)d_in[0];
    const int*   tour     = (const int*)  d_in[1];
    const float* eW       = (const float*)d_in[2];
    const float* eb       = (const float*)d_in[3];
    const float* enc_Wih  = (const float*)d_in[4];
    const float* enc_Whh  = (const float*)d_in[5];
    const float* enc_bih  = (const float*)d_in[6];
    const float* enc_bhh  = (const float*)d_in[7];
    const float* dec_Wih  = (const float*)d_in[8];
    const float* dec_Whh  = (const float*)d_in[9];
    const float* dec_bih  = (const float*)d_in[10];
    const float* dec_bhh  = (const float*)d_in[11];
    const float* W1       = (const float*)d_in[12];
    const float* W2       = (const float*)d_in[13];
    const float* attv     = (const float*)d_in[14];
    const float* cW       = (const float*)d_in[15];
    const float* cb       = (const float*)d_in[16];
    const float* st       = (const float*)d_in[17];
    float* out = (float*)d_out;

    float* ws = (float*)d_ws;
    size_t o = 0;
    float* emb    = ws + o; o += (size_t)N_*E_;
    float* city   = ws + o; o += (size_t)N_*E_;
    float* dseq   = ws + o; o += (size_t)N_*E_;
    float* exih   = ws + o; o += (size_t)N_*G4_;
    float* dxih   = ws + o; o += (size_t)N_*G4_;
    float* encout = ws + o; o += (size_t)N_*H_;
    float* hx     = ws + o; o += (size_t)N_*H_;
    float* projT  = ws + o; o += (size_t)N_*H_;   // [H_][N_] transposed (pre-scaled)
    float* Umat   = ws + o; o += (size_t)N_*H_;   // [N_][H_]  (pre-scaled)
    float* negv2  = ws + o; o += 256;
    float* sumv   = ws + o; o += 64;
    float* zero256= ws + o; o += 256;
    int* regs     = (int*)(ws + o); o += 64;
    int* pos      = (int*)(ws + o); o += N_;

    init_misc  <<<16, 256, 0, stream>>>(tour, attv, out + (size_t)N_*N_, pos, zero256, negv2, sumv, regs);
    fill_sent  <<<1024, 256, 0, stream>>>((uint4*)encout, (uint4*)hx);
    pos_scatter<<<16, 256, 0, stream>>>(tour, pos);
    embed2     <<<N_, 256, 0, stream>>>(x, eW, eb, cW, cb, emb, city);
    gather_dec <<<N_, 128, 0, stream>>>(city, st, tour, dseq);
    gemm64<<<dim3(G4_/64, N_/64), 256, 0, stream>>>(emb,  enc_Wih, exih, N_, G4_, E_, enc_bih, enc_bhh, 1.f, 0);
    gemm64<<<dim3(G4_/64, N_/64), 256, 0, stream>>>(dseq, dec_Wih, dxih, N_, G4_, E_, dec_bih, dec_bhh, 1.f, 0);
    lstm_scan4<<<NBLK_, 256, 0, stream>>>(exih, enc_Whh, dxih, dec_Whh, zero256, encout, hx, regs);
    gemm64<<<dim3(H_/64, N_/64), 256, 0, stream>>>(encout, W1, projT, N_, H_, H_, nullptr, nullptr, SCALE_T, 1);
    gemm64<<<dim3(H_/64, N_/64), 256, 0, stream>>>(hx,     W2, Umat,  N_, H_, H_, nullptr, nullptr, SCALE_T, 0);
    attn_scores<<<dim3(N_/TI_, N_/TT_), 256, 0, stream>>>(projT, Umat, negv2, sumv, pos, out);
    logsm<<<N_, 256, 0, stream>>>(out);
}